// Round 2
// baseline (137.308 us; speedup 1.0000x reference)
//
#include <hip/hip_runtime.h>
#include <hip/hip_bf16.h>
#include <math.h>

constexpr int kB = 128;
constexpr int kT = 256;
constexpr int kC = 384;
constexpr int kH = 64;

using bf16x8 = __attribute__((ext_vector_type(8))) short;  // 8 bf16 = 4 VGPRs
using f32x4  = __attribute__((ext_vector_type(4))) float;

union BF8 { bf16x8 v; __hip_bfloat162 h[4]; };
union BF4 { short4 s; __hip_bfloat162 h[2]; };

__device__ inline bf16x8 cvt8(float4 a, float4 b) {
    BF8 u;
    u.h[0] = __float22bfloat162_rn(float2{a.x, a.y});
    u.h[1] = __float22bfloat162_rn(float2{a.z, a.w});
    u.h[2] = __float22bfloat162_rn(float2{b.x, b.y});
    u.h[3] = __float22bfloat162_rn(float2{b.z, b.w});
    return u.v;
}
__device__ inline short4 cvt4(float4 a) {
    BF4 u;
    u.h[0] = __float22bfloat162_rn(float2{a.x, a.y});
    u.h[1] = __float22bfloat162_rn(float2{a.z, a.w});
    return u.s;
}
__device__ inline short bf1(float f) {
    __hip_bfloat16 h = __float2bfloat16(f);
    return *(short*)&h;
}

// ---------------------------------------------------------------------------
// Kernel 0: Wt[n][k] bf16, n in [0,192) = (w*64+h), k in [0,384).
// Wk rows pre-scaled by 384^-0.5 (k only feeds scores).
// ---------------------------------------------------------------------------
__global__ void prep_kernel(const float* __restrict__ Wq,
                            const float* __restrict__ Wk,
                            const float* __restrict__ Wv,
                            __hip_bfloat16* __restrict__ Wt) {
    int idx = blockIdx.x * 256 + threadIdx.x;     // [0, 192*384)
    int n = idx / kC, c = idx % kC;
    int w = n >> 6, h = n & 63;
    const float* W = (w == 0) ? Wq : (w == 1) ? Wk : Wv;
    float val = W[c * kH + h];
    if (w == 1) val *= 0.051031036307982884f;     // 384^-0.5
    Wt[idx] = __float2bfloat16(val);
}

// ---------------------------------------------------------------------------
// Fused kernel, 1024 threads (16 waves = 4/SIMD; was 512/2 — round-1 counters
// showed all pipes <12% busy at occupancy 19.6% => latency-bound).
// Block = (b, half) via XCD-pairing swizzle (round-robin puts the pair on one
// XCD's L2). Phase 1: M x 192 GEMM (M = 256 heavy / 128 light), BK=32,
// 12 K-steps, LDS double-buffered AND register double-buffered: tile s+2 is
// loaded to regs while tile s+1 (loaded a full step earlier) goes to LDS, so
// the global latency is covered by a whole step, not just one step's MFMA.
// 16 waves: wm=wave&3 (64-row m-band), wn=wave>>2 (3 n-tiles), acc[4][3].
// Dead-K skip: heavy wm<2 waves skip K n-tiles 4..7 (discarded by epilogue).
// Phase 2: waves pair up — band=wave>>1 (16 t-rows), piece=wave&1 splits the
// i-tile loop by parity (max 2 flash iters/wave, was 4); partial (m,l,O)
// merged via dead Bs LDS in two rounds (3 barriers). P staged as bf16 at
// stride 72 (16B-aligned reads, free bank class); 16 slots fill dead As.
// LDS: 36864(Qs)+18432(Ks)+33792(VTs)+36864(As x2)+27648(Bs x2)=153600 B.
// ---------------------------------------------------------------------------
__global__ __launch_bounds__(1024, 4) void fused_kernel(
    const float* __restrict__ x, const __hip_bfloat16* __restrict__ Wt,
    float* __restrict__ out)
{
    __shared__ __align__(16) short SM[76800];
    short* Qs  = SM;              // [s][h]    stride 72, 256 rows
    short* Ks  = SM + 18432;      // [t-t0][h] stride 72, 128 rows
    short* VTs = SM + 27648;      // [h][s]    stride 264, 64 rows
    short* As0 = SM + 44544;      // x tile bf16 [m][kk], stride 36
    short* As1 = SM + 53760;
    short* Bs0 = SM + 62976;      // Wt tile [n][kk], stride 36
    short* Bs1 = SM + 69888;

    const int bid  = blockIdx.x;
    const int b    = ((bid >> 4) << 3) | (bid & 7);   // batch
    const int half = ((bid >> 3) & 1) ^ 1;            // heavy (1) first
    const int t0   = half * 128;

    const int tid  = threadIdx.x;
    const int wave = tid >> 6, lane = tid & 63;
    const int m16  = lane & 15, quad = lane >> 4;
    const int wm = wave & 3, wn = wave >> 2;          // m-band, 3-n-tile slice
    const short* wt = (const short*)Wt;
    const float* xb = x + (size_t)b * kT * kC;

    // wave-uniform activity masks for the light half (M = 128)
    const bool mfmaAct = (half == 1) || (wm < 2);

    // dead-K: heavy half's rows 0-127 K-projection is discarded -> skip
    bool kskip[3];
#pragma unroll
    for (int j = 0; j < 3; ++j) {
        const int nt = wn * 3 + j;
        kskip[j] = (half == 1) && (wm < 2) && (nt >= 4) && (nt < 8);
    }

    // ---------------- Phase 1: projection ----------------
    // A staging: 4 threads/row, 8 fp32 each (waves 0-7 -> rows 0-127).
    const int arow = tid >> 2, acol = (tid & 3) * 8;
    const bool aAct = (half == 1) || (arow < 128);    // <=> wave < 8
    const bool bAct = (tid < 768);                    // <=> wave < 12

    float4 la0[2], la1[2]; bf16x8 lb0, lb1;
    auto glod = [&](float4* la, bf16x8& lb, int k0) {
        if (aAct) {
            la[0] = *(const float4*)(xb + (size_t)arow * kC + k0 + acol);
            la[1] = *(const float4*)(xb + (size_t)arow * kC + k0 + acol + 4);
        }
        if (bAct)
            lb = *(const bf16x8*)(wt + (size_t)(tid >> 2) * kC + k0 + (tid & 3) * 8);
    };
    auto swr = [&](short* Ad, short* Bd, const float4* la, const bf16x8& lb) {
        if (aAct) {
            *(short4*)&Ad[arow * 36 + acol]     = cvt4(la[0]);
            *(short4*)&Ad[arow * 36 + acol + 4] = cvt4(la[1]);
        }
        if (bAct)
            *(bf16x8*)&Bd[(tid >> 2) * 36 + (tid & 3) * 8] = lb;
    };

    f32x4 acc[4][3];
#pragma unroll
    for (int mt = 0; mt < 4; ++mt)
#pragma unroll
        for (int j = 0; j < 3; ++j) acc[mt][j] = f32x4{0.f, 0.f, 0.f, 0.f};

    auto mstep = [&](const short* Ad, const short* Bd) {
        if (!mfmaAct) return;
        bf16x8 af[4];
#pragma unroll
        for (int mt = 0; mt < 4; ++mt)
            af[mt] = *(const bf16x8*)&Ad[(wm * 64 + mt * 16 + m16) * 36 + quad * 8];
#pragma unroll
        for (int j = 0; j < 3; ++j) {
            if (!kskip[j]) {
                const bf16x8 bfr =
                    *(const bf16x8*)&Bd[((wn * 3 + j) * 16 + m16) * 36 + quad * 8];
#pragma unroll
                for (int mt = 0; mt < 4; ++mt)
                    acc[mt][j] = __builtin_amdgcn_mfma_f32_16x16x32_bf16(
                        af[mt], bfr, acc[mt][j], 0, 0, 0);
            }
        }
    };

    // prologue: tiles 0,1 in regs; tile 0 -> LDS buf0
    glod(la0, lb0, 0);
    glod(la1, lb1, 32);
    swr(As0, Bs0, la0, lb0);
    __syncthreads();

    for (int s = 0; s < 12; s += 2) {
        // even step: compute buf0 (tile s); load tile s+2; write buf1 <- tile s+1
        if (s < 10) glod(la0, lb0, (s + 2) * 32);
        mstep(As0, Bs0);
        swr(As1, Bs1, la1, lb1);
        __syncthreads();
        // odd step: compute buf1 (tile s+1); load tile s+3; write buf0 <- tile s+2
        if (s + 1 < 10) glod(la1, lb1, (s + 3) * 32);
        mstep(As1, Bs1);
        if (s + 1 < 11) swr(As0, Bs0, la0, lb0);
        __syncthreads();
    }

    // epilogue: C-layout (col = m16, rows = quad*4+r) -> LDS homes
    if (mfmaAct) {
#pragma unroll
        for (int mt = 0; mt < 4; ++mt) {
            const int mbase = wm * 64 + mt * 16 + quad * 4;
#pragma unroll
            for (int j = 0; j < 3; ++j) {
                const int nt = wn * 3 + j;             // n-tile 0..11
                const int w  = nt >> 2;                // 0=q, 1=k, 2=v
                const int h  = (nt & 3) * 16 + m16;
                if (w == 2) {
                    float4 f = make_float4(acc[mt][j][0], acc[mt][j][1],
                                           acc[mt][j][2], acc[mt][j][3]);
                    *(short4*)&VTs[h * 264 + mbase] = cvt4(f);   // s = mbase..+3
                } else if (w == 1) {
                    if ((mbase >> 7) == half) {        // rows [t0, t0+128)
#pragma unroll
                        for (int r = 0; r < 4; ++r)
                            Ks[(mbase + r - t0) * 72 + h] = bf1(acc[mt][j][r]);
                    }
                } else {
#pragma unroll
                    for (int r = 0; r < 4; ++r)
                        Qs[(mbase + r) * 72 + h] = bf1(acc[mt][j][r]);
                }
            }
        }
    }
    __syncthreads();   // phase boundary: Qs/Ks/VTs all visible

    // ---------------- Phase 2: attention (pair-split flash) ----------------
    const int band  = wave >> 1;                   // 0..7: t-band of 16 rows
    const int piece = wave & 1;                    // i-tile parity
    const int wband = t0 + band * 16;
    short* Pb = As0 + wave * 1152;                 // per-wave 16x72 bf16 P tile

    const bf16x8 ka0 = *(const bf16x8*)&Ks[(band * 16 + m16) * 72 + quad * 8];
    const bf16x8 ka1 = *(const bf16x8*)&Ks[(band * 16 + m16) * 72 + quad * 8 + 32];

    f32x4 O[4];
    float m_[4], l_[4];
#pragma unroll
    for (int i = 0; i < 4; ++i) {
        O[i] = f32x4{0.f, 0.f, 0.f, 0.f};
        m_[i] = -INFINITY; l_[i] = 0.f;
    }

    const int ilast = wband >> 6;
    for (int i = piece; i <= ilast; i += 2) {
        const bool diag = (i == ilast);
        const int jmax = diag ? (band & 3) : 3;    // wave-uniform

        f32x4 S[4];
        const f32x4 Z = f32x4{0.f, 0.f, 0.f, 0.f};
#pragma unroll
        for (int j = 0; j < 4; ++j) {
            if (j <= jmax) {
                bf16x8 qb0 = *(const bf16x8*)&Qs[(i * 64 + j * 16 + m16) * 72 + quad * 8];
                bf16x8 qb1 = *(const bf16x8*)&Qs[(i * 64 + j * 16 + m16) * 72 + quad * 8 + 32];
                S[j] = __builtin_amdgcn_mfma_f32_16x16x32_bf16(ka0, qb0, Z, 0, 0, 0);
                S[j] = __builtin_amdgcn_mfma_f32_16x16x32_bf16(ka1, qb1, S[j], 0, 0, 0);
            }
        }
        if (diag) {    // j == jmax tile straddles the diagonal
#pragma unroll
            for (int r = 0; r < 4; ++r)
                if (m16 > quad * 4 + r) S[jmax][r] = -INFINITY;
        }

        float P[4][4];
#pragma unroll
        for (int j = 0; j < 4; ++j)
#pragma unroll
            for (int r = 0; r < 4; ++r) P[j][r] = 0.f;
#pragma unroll
        for (int r = 0; r < 4; ++r) {
            float rm = -INFINITY;
#pragma unroll
            for (int j = 0; j < 4; ++j)
                if (j <= jmax) rm = fmaxf(rm, S[j][r]);
            rm = fmaxf(rm, __shfl_xor(rm, 1, 64));
            rm = fmaxf(rm, __shfl_xor(rm, 2, 64));
            rm = fmaxf(rm, __shfl_xor(rm, 4, 64));
            rm = fmaxf(rm, __shfl_xor(rm, 8, 64));
            const float mn = fmaxf(m_[r], rm);
            const float al = __expf(m_[r] - mn);
            m_[r] = mn;
            float rs = 0.f;
#pragma unroll
            for (int j = 0; j < 4; ++j) {
                if (j <= jmax) { P[j][r] = __expf(S[j][r] - mn); rs += P[j][r]; }
            }
            rs += __shfl_xor(rs, 1, 64);
            rs += __shfl_xor(rs, 2, 64);
            rs += __shfl_xor(rs, 4, 64);
            rs += __shfl_xor(rs, 8, 64);
            l_[r] = l_[r] * al + rs;
            O[0][r] *= al; O[1][r] *= al; O[2][r] *= al; O[3][r] *= al;
        }

        // P: C-layout bf16 write (zeros beyond jmax), A-layout b128 read
#pragma unroll
        for (int j = 0; j < 4; ++j)
#pragma unroll
            for (int r = 0; r < 4; ++r)
                Pb[(quad * 4 + r) * 72 + j * 16 + m16] = bf1(P[j][r]);
        bf16x8 pf0 = *(const bf16x8*)&Pb[m16 * 72 + quad * 8];
        bf16x8 pf1 = *(const bf16x8*)&Pb[m16 * 72 + quad * 8 + 32];

        // O += P @ V  (V from LDS, [h][s])
#pragma unroll
        for (int ht = 0; ht < 4; ++ht) {
            bf16x8 vb0 = *(const bf16x8*)&VTs[(ht * 16 + m16) * 264 + i * 64 + quad * 8];
            bf16x8 vb1 = *(const bf16x8*)&VTs[(ht * 16 + m16) * 264 + i * 64 + quad * 8 + 32];
            O[ht] = __builtin_amdgcn_mfma_f32_16x16x32_bf16(pf0, vb0, O[ht], 0, 0, 0);
            O[ht] = __builtin_amdgcn_mfma_f32_16x16x32_bf16(pf1, vb1, O[ht], 0, 0, 0);
        }
    }

    // ---- merge the two pieces of each band via dead Bs LDS (two rounds) ----
    float* MB = (float*)Bs0;                       // 4 slots x 64 lanes x 25 f32
    auto mbWrite = [&](int slot) {
        float* p = MB + ((size_t)slot * 64 + lane) * 25;
#pragma unroll
        for (int r = 0; r < 4; ++r) { p[r] = m_[r]; p[4 + r] = l_[r]; }
#pragma unroll
        for (int ht = 0; ht < 4; ++ht)
#pragma unroll
            for (int r = 0; r < 4; ++r) p[8 + ht * 4 + r] = O[ht][r];
    };
    auto mergeOut = [&](int slot) {
        const float* p = MB + ((size_t)slot * 64 + lane) * 25;
#pragma unroll
        for (int r = 0; r < 4; ++r) {
            const float m1 = p[r], l1 = p[4 + r];
            const float mn = fmaxf(m_[r], m1);
            const float a0 = __expf(m_[r] - mn), a1 = __expf(m1 - mn);
            const float linv = 1.f / (l_[r] * a0 + l1 * a1);
            const size_t row = (size_t)(b * kT + wband + quad * 4 + r);
#pragma unroll
            for (int ht = 0; ht < 4; ++ht)
                out[row * kH + ht * 16 + m16] =
                    (O[ht][r] * a0 + p[8 + ht * 4 + r] * a1) * linv;
        }
    };

    if (piece == 1 && band < 4) mbWrite(band);
    __syncthreads();
    if (piece == 0 && band < 4) mergeOut(band);
    __syncthreads();
    if (piece == 1 && band >= 4) mbWrite(band - 4);
    __syncthreads();
    if (piece == 0 && band >= 4) mergeOut(band - 4);
}

// ---------------------------------------------------------------------------
extern "C" void kernel_launch(void* const* d_in, const int* in_sizes, int n_in,
                              void* d_out, int out_size, void* d_ws, size_t ws_size,
                              hipStream_t stream) {
    const float* x  = (const float*)d_in[0];
    const float* Wq = (const float*)d_in[1];
    const float* Wk = (const float*)d_in[2];
    const float* Wv = (const float*)d_in[3];
    float* out = (float*)d_out;

    __hip_bfloat16* Wt = (__hip_bfloat16*)d_ws;    // 147 KB [n][k]

    prep_kernel<<<(192 * kC) / 256, 256, 0, stream>>>(Wq, Wk, Wv, Wt);
    fused_kernel<<<dim3(256), 1024, 0, stream>>>(x, Wt, out);
}

// Round 3
// 122.109 us; speedup vs baseline: 1.1245x; 1.1245x over previous
//
#include <hip/hip_runtime.h>
#include <hip/hip_bf16.h>
#include <math.h>

constexpr int kB = 128;
constexpr int kT = 256;
constexpr int kC = 384;
constexpr int kH = 64;

using bf16x8 = __attribute__((ext_vector_type(8))) short;  // 8 bf16 = 4 VGPRs
using f32x4  = __attribute__((ext_vector_type(4))) float;

union BF4 { short4 s; __hip_bfloat162 h[2]; };

__device__ inline short4 cvt4(float4 a) {
    BF4 u;
    u.h[0] = __float22bfloat162_rn(float2{a.x, a.y});
    u.h[1] = __float22bfloat162_rn(float2{a.z, a.w});
    return u.s;
}
__device__ inline short bf1(float f) {
    __hip_bfloat16 h = __float2bfloat16(f);
    return *(short*)&h;
}

// ---------------------------------------------------------------------------
// Kernel 0: Wt[n][k] bf16, n in [0,192) = (w*64+h), k in [0,384).
// Wk rows pre-scaled by 384^-0.5 (k only feeds scores).
// ---------------------------------------------------------------------------
__global__ void prep_kernel(const float* __restrict__ Wq,
                            const float* __restrict__ Wk,
                            const float* __restrict__ Wv,
                            __hip_bfloat16* __restrict__ Wt) {
    int idx = blockIdx.x * 256 + threadIdx.x;     // [0, 192*384)
    int n = idx / kC, c = idx % kC;
    int w = n >> 6, h = n & 63;
    const float* W = (w == 0) ? Wq : (w == 1) ? Wk : Wv;
    float val = W[c * kH + h];
    if (w == 1) val *= 0.051031036307982884f;     // 384^-0.5
    Wt[idx] = __float2bfloat16(val);
}

// ---------------------------------------------------------------------------
// Kernel 1: projection GEMM. 512 blocks x 256 threads; block = (q4, b) with
// bid = q4*128 + b so bid%8 == b%8 (XCD round-robin pins each batch's qkv to
// one XCD's L2 — the attention kernel uses the same mapping to read it back).
// Each block: 64-row stripe x 192 cols, K=384, BK=32, LDS double-buffered.
// 37 KB LDS + <=128 VGPR (__launch_bounds__(256,4)) => 4 blocks/CU =
// 16 waves/CU — barrier scope is 4 waves, latency hides via TLP across
// blocks (round-2 post-mortem: the 1-block/CU monolith was the bottleneck).
// Wave wn in [0,4) owns 3 n-tiles (48 cols) over all 64 rows: acc[4][3].
// No dead work (fused version computed+discarded half the K rows).
// Outputs per batch: Q[s][h], K[t][h] (scaled), VT[h][s] — all bf16.
// ---------------------------------------------------------------------------
__global__ __launch_bounds__(256, 4) void proj_kernel(
    const float* __restrict__ x, const __hip_bfloat16* __restrict__ Wt,
    short* __restrict__ Qg, short* __restrict__ Kg, short* __restrict__ VTg)
{
    __shared__ short As[2][64 * 36];    // x tile bf16 [m][kk], stride 36
    __shared__ short Bs[2][192 * 36];   // Wt tile    [n][kk], stride 36

    const int bid = blockIdx.x;
    const int b   = bid & 127;          // batch
    const int q4  = bid >> 7;           // row-quarter of the batch
    const int row0 = b * kT + q4 * 64;  // global x row base

    const int tid  = threadIdx.x;
    const int wave = tid >> 6, lane = tid & 63;
    const int m16  = lane & 15, quad = lane >> 4;
    const short* wt = (const short*)Wt;

    // A staging: 4 threads/row, 8 fp32 each. B staging: 3 bf16x8 chunks/thread.
    const int arow = tid >> 2, acol = (tid & 3) * 8;
    const float* xr = x + (size_t)(row0 + arow) * kC;

    float4 la[2]; bf16x8 lb[3];
    auto glod = [&](int k0) {
        la[0] = *(const float4*)(xr + k0 + acol);
        la[1] = *(const float4*)(xr + k0 + acol + 4);
#pragma unroll
        for (int p = 0; p < 3; ++p) {
            int c = tid + 256 * p, n = c >> 2, kk = (c & 3) * 8;
            lb[p] = *(const bf16x8*)(wt + (size_t)n * kC + k0 + kk);
        }
    };
    auto swr = [&](int d) {
        *(short4*)&As[d][arow * 36 + acol]     = cvt4(la[0]);
        *(short4*)&As[d][arow * 36 + acol + 4] = cvt4(la[1]);
#pragma unroll
        for (int p = 0; p < 3; ++p) {
            int c = tid + 256 * p, n = c >> 2, kk = (c & 3) * 8;
            *(bf16x8*)&Bs[d][n * 36 + kk] = lb[p];
        }
    };

    f32x4 acc[4][3];
#pragma unroll
    for (int mt = 0; mt < 4; ++mt)
#pragma unroll
        for (int j = 0; j < 3; ++j) acc[mt][j] = f32x4{0.f, 0.f, 0.f, 0.f};

    glod(0);
    swr(0);
    __syncthreads();

    for (int s = 0; s < 12; ++s) {
        const int d = s & 1;
        if (s < 11) glod((s + 1) * 32);            // next tile in flight

        bf16x8 af[4];
#pragma unroll
        for (int mt = 0; mt < 4; ++mt)
            af[mt] = *(const bf16x8*)&As[d][(mt * 16 + m16) * 36 + quad * 8];
#pragma unroll
        for (int j = 0; j < 3; ++j) {
            const bf16x8 bfr =
                *(const bf16x8*)&Bs[d][((wave * 3 + j) * 16 + m16) * 36 + quad * 8];
#pragma unroll
            for (int mt = 0; mt < 4; ++mt)
                acc[mt][j] = __builtin_amdgcn_mfma_f32_16x16x32_bf16(
                    af[mt], bfr, acc[mt][j], 0, 0, 0);
        }

        if (s < 11) swr(d ^ 1);
        __syncthreads();
    }

    // epilogue: C-layout (col = m16, rows = quad*4+r) -> global qkv homes
#pragma unroll
    for (int mt = 0; mt < 4; ++mt) {
        const int mrow = mt * 16 + quad * 4;       // within the 64-row stripe
#pragma unroll
        for (int j = 0; j < 3; ++j) {
            const int nt = wave * 3 + j;           // n-tile 0..11
            const int w  = nt >> 2;                // 0=q, 1=k, 2=v
            const int h  = (nt & 3) * 16 + m16;
            if (w == 2) {
                float4 f = make_float4(acc[mt][j][0], acc[mt][j][1],
                                       acc[mt][j][2], acc[mt][j][3]);
                *(short4*)&VTg[((size_t)b * kH + h) * kT + q4 * 64 + mrow] = cvt4(f);
            } else {
                short* G = (w == 1) ? Kg : Qg;
#pragma unroll
                for (int r = 0; r < 4; ++r)
                    G[((size_t)b * kT + q4 * 64 + mrow + r) * kH + h] = bf1(acc[mt][j][r]);
            }
        }
    }
}

// ---------------------------------------------------------------------------
// Kernel 2: attention. 512 blocks x 256 threads; block = (b, qi) with
// b = ((bid>>5)<<3)|(bid&7), qi = (bid>>3)&3 — bid%8 == b%8, matching the
// producer's XCD so the 96 KB/batch qkv working set is an L2 hit.
// Wave owns t-band [qi*64 + wave*16, +16); flash loop over i <= qi with
// Q/K/V MFMA fragments loaded DIRECTLY from global (L2) — zero barriers,
// only per-wave P-transpose buffers in LDS (9 KB) => many blocks/CU, and
// the serial softmax chain hides across independent blocks instead of
// being locked behind block-wide barriers (round-1/2 bottleneck).
// wei[t,s] = k[t]·q[s] (k pre-scaled), causal s<=t, out[t] = P[t,:] @ V.
// ---------------------------------------------------------------------------
__global__ __launch_bounds__(256, 4) void attn_kernel(
    const short* __restrict__ Qg, const short* __restrict__ Kg,
    const short* __restrict__ VTg, float* __restrict__ out)
{
    __shared__ short Pbuf[4][16 * 72];             // per-wave P tile, stride 72

    const int bid = blockIdx.x;
    const int b   = ((bid >> 5) << 3) | (bid & 7); // batch
    const int qi  = (bid >> 3) & 3;                // row-quarter

    const int tid  = threadIdx.x;
    const int wave = tid >> 6, lane = tid & 63;
    const int m16  = lane & 15, quad = lane >> 4;
    const int trow0 = qi * 64 + wave * 16;         // this wave's t-band

    const short* Qb = Qg  + (size_t)b * kT * kH;
    const short* Kb = Kg  + (size_t)b * kT * kH;
    const short* Vb = VTg + (size_t)b * kH * kT;
    short* Pb = Pbuf[wave];

    const bf16x8 ka0 = *(const bf16x8*)&Kb[(trow0 + m16) * kH + quad * 8];
    const bf16x8 ka1 = *(const bf16x8*)&Kb[(trow0 + m16) * kH + quad * 8 + 32];

    f32x4 O[4];
    float m_[4], l_[4];
#pragma unroll
    for (int i = 0; i < 4; ++i) {
        O[i] = f32x4{0.f, 0.f, 0.f, 0.f};
        m_[i] = -INFINITY; l_[i] = 0.f;
    }

    for (int i = 0; i <= qi; ++i) {
        const bool diag = (i == qi);
        const int jmax = diag ? wave : 3;          // wave-uniform

        f32x4 S[4];
        const f32x4 Z = f32x4{0.f, 0.f, 0.f, 0.f};
#pragma unroll
        for (int j = 0; j < 4; ++j) {
            if (j <= jmax) {
                const int s = i * 64 + j * 16 + m16;
                bf16x8 qb0 = *(const bf16x8*)&Qb[s * kH + quad * 8];
                bf16x8 qb1 = *(const bf16x8*)&Qb[s * kH + quad * 8 + 32];
                S[j] = __builtin_amdgcn_mfma_f32_16x16x32_bf16(ka0, qb0, Z, 0, 0, 0);
                S[j] = __builtin_amdgcn_mfma_f32_16x16x32_bf16(ka1, qb1, S[j], 0, 0, 0);
            }
        }
        if (diag) {    // j == jmax tile straddles the diagonal (s > t masked)
#pragma unroll
            for (int r = 0; r < 4; ++r)
                if (m16 > quad * 4 + r) S[jmax][r] = -INFINITY;
        }

        float P[4][4];
#pragma unroll
        for (int j = 0; j < 4; ++j)
#pragma unroll
            for (int r = 0; r < 4; ++r) P[j][r] = 0.f;
#pragma unroll
        for (int r = 0; r < 4; ++r) {
            float rm = -INFINITY;
#pragma unroll
            for (int j = 0; j < 4; ++j)
                if (j <= jmax) rm = fmaxf(rm, S[j][r]);
            rm = fmaxf(rm, __shfl_xor(rm, 1, 64));
            rm = fmaxf(rm, __shfl_xor(rm, 2, 64));
            rm = fmaxf(rm, __shfl_xor(rm, 4, 64));
            rm = fmaxf(rm, __shfl_xor(rm, 8, 64));
            const float mn = fmaxf(m_[r], rm);
            const float al = __expf(m_[r] - mn);
            m_[r] = mn;
            float rs = 0.f;
#pragma unroll
            for (int j = 0; j < 4; ++j) {
                if (j <= jmax) { P[j][r] = __expf(S[j][r] - mn); rs += P[j][r]; }
            }
            rs += __shfl_xor(rs, 1, 64);
            rs += __shfl_xor(rs, 2, 64);
            rs += __shfl_xor(rs, 4, 64);
            rs += __shfl_xor(rs, 8, 64);
            l_[r] = l_[r] * al + rs;
            O[0][r] *= al; O[1][r] *= al; O[2][r] *= al; O[3][r] *= al;
        }

        // P: C-layout bf16 write (zeros beyond jmax), A-layout b128 read
#pragma unroll
        for (int j = 0; j < 4; ++j)
#pragma unroll
            for (int r = 0; r < 4; ++r)
                Pb[(quad * 4 + r) * 72 + j * 16 + m16] = bf1(P[j][r]);
        bf16x8 pf0 = *(const bf16x8*)&Pb[m16 * 72 + quad * 8];
        bf16x8 pf1 = *(const bf16x8*)&Pb[m16 * 72 + quad * 8 + 32];

        // O += P @ V  (VT[h][s] from global/L2)
#pragma unroll
        for (int ht = 0; ht < 4; ++ht) {
            bf16x8 vb0 = *(const bf16x8*)&Vb[(ht * 16 + m16) * kT + i * 64 + quad * 8];
            bf16x8 vb1 = *(const bf16x8*)&Vb[(ht * 16 + m16) * kT + i * 64 + quad * 8 + 32];
            O[ht] = __builtin_amdgcn_mfma_f32_16x16x32_bf16(pf0, vb0, O[ht], 0, 0, 0);
            O[ht] = __builtin_amdgcn_mfma_f32_16x16x32_bf16(pf1, vb1, O[ht], 0, 0, 0);
        }
    }

    // epilogue
#pragma unroll
    for (int r = 0; r < 4; ++r) {
        const float inv = 1.f / l_[r];
        const size_t row = (size_t)(b * kT + trow0 + quad * 4 + r);
#pragma unroll
        for (int ht = 0; ht < 4; ++ht)
            out[row * kH + ht * 16 + m16] = O[ht][r] * inv;
    }
}

// ---------------------------------------------------------------------------
extern "C" void kernel_launch(void* const* d_in, const int* in_sizes, int n_in,
                              void* d_out, int out_size, void* d_ws, size_t ws_size,
                              hipStream_t stream) {
    const float* x  = (const float*)d_in[0];
    const float* Wq = (const float*)d_in[1];
    const float* Wk = (const float*)d_in[2];
    const float* Wv = (const float*)d_in[3];
    float* out = (float*)d_out;

    // workspace layout (bf16 as short): Wt | Q | K | VT
    short* base = (short*)d_ws;
    __hip_bfloat16* Wt = (__hip_bfloat16*)base;            // 192*384 = 73728
    short* Qg  = base + 73728;                             // 128*256*64
    short* Kg  = Qg + (size_t)kB * kT * kH;
    short* VTg = Kg + (size_t)kB * kT * kH;

    prep_kernel<<<(192 * kC) / 256, 256, 0, stream>>>(Wq, Wk, Wv, Wt);
    proj_kernel<<<dim3(512), 256, 0, stream>>>(x, Wt, Qg, Kg, VTg);
    attn_kernel<<<dim3(512), 256, 0, stream>>>(Qg, Kg, VTg, out);
}